// Round 1
// baseline (322.514 us; speedup 1.0000x reference)
//
#include <hip/hip_runtime.h>
#include <math.h>

// Problem constants (from reference setup_inputs)
#define L0      3072
#define DIM     128
#define BATCH   1024
#define NNEG    512

// -------- workspace layout (float offsets) --------
// X0   : 0                (3072*128)   feat @ w_self_0
// Y0   : 393216           (3072*128)   feat @ w_neigh_0
// H    : 786432           (3072*512)   [self1 | neigh_mean1] (layer-1 inputs)
// R    : 2359296          (3072*256)   layer-1 output, normalized in place
// aff  : 3145728          (1024)
// spPos: 3146752          (1)
// spNeg: 3146753          (1)
// rank : 3146754          (1024 ints)

// K1: X0 = feat @ ws0, Y0 = feat @ wn0.  8 feat rows per block.
__global__ __launch_bounds__(256) void k_transform(
    const float* __restrict__ feat, const float* __restrict__ ws0,
    const float* __restrict__ wn0, float* __restrict__ X0, float* __restrict__ Y0) {
  const int t = threadIdx.x;
  const int rowBase = blockIdx.x * 8;
  const bool selfHalf = (t < 128);
  const int col = selfHalf ? t : (t - 128);
  const float* __restrict__ W = selfHalf ? ws0 : wn0;
  float acc[8];
#pragma unroll
  for (int r = 0; r < 8; ++r) acc[r] = 0.f;
  for (int k = 0; k < 128; k += 4) {
    float4 f[8];
#pragma unroll
    for (int r = 0; r < 8; ++r)
      f[r] = *(const float4*)&feat[(rowBase + r) * 128 + k];  // uniform -> s_load
#pragma unroll
    for (int kk = 0; kk < 4; ++kk) {
      float w = W[(k + kk) * 128 + col];
#pragma unroll
      for (int r = 0; r < 8; ++r)
        acc[r] = fmaf(((const float*)&f[r])[kk], w, acc[r]);
    }
  }
  float* __restrict__ Out = selfHalf ? X0 : Y0;
#pragma unroll
  for (int r = 0; r < 8; ++r) Out[(rowBase + r) * 128 + col] = acc[r];
}

// K2: fused layer-0 (relu(concat[X0, meanY0])) + layer-1 aggregation.
// One block per output node i. Produces H[i] = [self1(256) | neigh_mean1(256)].
__global__ __launch_bounds__(256) void k_aggregate(
    const float* __restrict__ X0, const float* __restrict__ Y0,
    const int* __restrict__ nb0, const int* __restrict__ nb1,
    const int* __restrict__ nb2, float* __restrict__ H) {
  __shared__ float nsum[256];
  const int i = blockIdx.x;
  const int t = threadIdx.x;
  const int c = t & 127;
  const int g = t >> 7;

  // self1 = h_hop0_l0[i] = relu([X0[nb0[i]], mean10 Y0[nb1[10i+j]]])
  float accS;
  if (t < 128) {
    accS = fmaxf(X0[nb0[i] * 128 + t], 0.f);
  } else {
    float s = 0.f;
#pragma unroll
    for (int j = 0; j < 10; ++j) s += Y0[nb1[i * 10 + j] * 128 + c];
    accS = fmaxf(s * 0.1f, 0.f);
  }

  // neigh_mean1 = mean_j relu([X0[nb1[r]], mean25 Y0[nb2[25r+k]]])
  float accN = 0.f;
  for (int j = 0; j < 10; ++j) {
    const int r = i * 10 + j;
    const int b2 = r * 25;
    float p = 0.f;
    for (int k = g; k < 25; k += 2)       // two lane-groups split the 25 rows
      p += Y0[nb2[b2 + k] * 128 + c];
    nsum[t] = p;
    __syncthreads();
    float hj;
    if (t < 128) hj = fmaxf(X0[nb1[r] * 128 + t], 0.f);
    else         hj = fmaxf((nsum[c] + nsum[c + 128]) * 0.04f, 0.f);
    accN += hj;
    __syncthreads();
  }
  H[i * 512 + t] = accS;
  H[i * 512 + 256 + t] = accN * 0.1f;
}

// K3: R = concat[self1 @ ws1, neigh_mean1 @ wn1].  16 nodes per block.
__global__ __launch_bounds__(256) void k_layer1(
    const float* __restrict__ H, const float* __restrict__ ws1,
    const float* __restrict__ wn1, float* __restrict__ R) {
  const int t = threadIdx.x;
  const int base = blockIdx.x * 16;
  const bool selfHalf = (t < 128);
  const int wcol = selfHalf ? t : (t - 128);
  const int hoff = selfHalf ? 0 : 256;
  const float* __restrict__ W = selfHalf ? ws1 : wn1;
  float acc[16];
#pragma unroll
  for (int r = 0; r < 16; ++r) acc[r] = 0.f;
  for (int d = 0; d < 256; d += 4) {
    float4 h4[16];
#pragma unroll
    for (int r = 0; r < 16; ++r)
      h4[r] = *(const float4*)&H[(base + r) * 512 + hoff + d];  // uniform -> s_load
#pragma unroll
    for (int dd = 0; dd < 4; ++dd) {
      float w = W[(d + dd) * 128 + wcol];
#pragma unroll
      for (int r = 0; r < 16; ++r)
        acc[r] = fmaf(((const float*)&h4[r])[dd], w, acc[r]);
    }
  }
#pragma unroll
  for (int r = 0; r < 16; ++r) R[(base + r) * 256 + t] = acc[r];
}

// K4: in-place L2 normalize each row of R.
__global__ __launch_bounds__(256) void k_normalize(float* __restrict__ R) {
  const int i = blockIdx.x;
  const int t = threadIdx.x;
  float v = R[i * 256 + t];
  float s = v * v;
#pragma unroll
  for (int off = 32; off > 0; off >>= 1) s += __shfl_down(s, off, 64);
  __shared__ float wsum[4];
  __shared__ float rnorm;
  if ((t & 63) == 0) wsum[t >> 6] = s;
  __syncthreads();
  if (t == 0) {
    float tot = wsum[0] + wsum[1] + wsum[2] + wsum[3];
    rnorm = rsqrtf(fmaxf(tot, 1e-12f));
  }
  __syncthreads();
  R[i * 256 + t] = v * rnorm;
}

__device__ __forceinline__ float softplusf(float x) {
  return fmaxf(x, 0.f) + log1pf(expf(-fabsf(x)));
}

// K5: write src_emb to d_out; aff[b] = dot(O[src], O[pos]) with the SAME
// sequential fmaf order as k_neg (exact-tie reproduction); accumulate
// softplus(-aff).
__global__ __launch_bounds__(256) void k_aff(
    const float* __restrict__ O, const int* __restrict__ src_idx,
    const int* __restrict__ pos_idx, float* __restrict__ out_src,
    float* __restrict__ aff, float* __restrict__ spPos) {
  const int b = blockIdx.x;
  const int t = threadIdx.x;
  const int s = src_idx[b];
  out_src[b * 256 + t] = O[s * 256 + t];
  if (t == 0) {
    const int p = pos_idx[b];
    float a = 0.f;
    for (int d = 0; d < 256; ++d) a = fmaf(O[s * 256 + d], O[p * 256 + d], a);
    aff[b] = a;
    atomicAdd(spPos, softplusf(-a));
  }
}

// K6: neg_aff tile (32 src rows x 64 neg cols per block), accumulating
// softplus sum and per-row rank counts (neg_aff >= aff, ties count — positive
// sorts last in the reference's stable argsort).
__global__ __launch_bounds__(256) void k_neg(
    const float* __restrict__ O, const int* __restrict__ src_idx,
    const int* __restrict__ neg_idx, const float* __restrict__ aff,
    int* __restrict__ rank, float* __restrict__ spNeg) {
  __shared__ float SL[32][129];
  __shared__ float NL[64][129];
  __shared__ float affL[32];
  __shared__ int cntL[32];
  const int t = threadIdx.x;
  const int rowBase = (blockIdx.x >> 3) * 32;
  const int colBase = (blockIdx.x & 7) * 64;
  if (t < 32) { affL[t] = aff[rowBase + t]; cntL[t] = 0; }
  const int ct = t & 31;
  const int rt = t >> 5;
  float acc[4][2];
#pragma unroll
  for (int k = 0; k < 4; ++k) { acc[k][0] = 0.f; acc[k][1] = 0.f; }
  for (int ch = 0; ch < 2; ++ch) {
    __syncthreads();
    for (int idx = t; idx < 32 * 128; idx += 256) {
      int r = idx >> 7, dd = idx & 127;
      SL[r][dd] = O[src_idx[rowBase + r] * 256 + ch * 128 + dd];
    }
    for (int idx = t; idx < 64 * 128; idx += 256) {
      int cpos = idx >> 7, dd = idx & 127;
      NL[cpos][dd] = O[neg_idx[colBase + cpos] * 256 + ch * 128 + dd];
    }
    __syncthreads();
    for (int dd = 0; dd < 128; ++dd) {
      float n0 = NL[ct][dd], n1 = NL[ct + 32][dd];
#pragma unroll
      for (int k = 0; k < 4; ++k) {
        float sv = SL[rt + 8 * k][dd];
        acc[k][0] = fmaf(sv, n0, acc[k][0]);
        acc[k][1] = fmaf(sv, n1, acc[k][1]);
      }
    }
  }
  float sp = 0.f;
#pragma unroll
  for (int k = 0; k < 4; ++k) {
    float a = affL[rt + 8 * k];
    int cnt = 0;
#pragma unroll
    for (int cc = 0; cc < 2; ++cc) {
      float v = acc[k][cc];
      sp += softplusf(v);
      cnt += (v >= a) ? 1 : 0;
    }
    if (cnt) atomicAdd(&cntL[rt + 8 * k], cnt);
  }
#pragma unroll
  for (int off = 32; off > 0; off >>= 1) sp += __shfl_down(sp, off, 64);
  if ((t & 63) == 0) atomicAdd(spNeg, sp);
  __syncthreads();
  if (t < 32) atomicAdd(&rank[rowBase + t], cntL[t]);
}

// K7: mrr + loss scalars.
__global__ __launch_bounds__(256) void k_finalize(
    const int* __restrict__ rank, const float* __restrict__ spPos,
    const float* __restrict__ spNeg, float* __restrict__ out) {
  const int t = threadIdx.x;
  float s = 0.f;
  for (int i = t; i < BATCH; i += 256) s += 1.f / (float)(rank[i] + 1);
#pragma unroll
  for (int off = 32; off > 0; off >>= 1) s += __shfl_down(s, off, 64);
  __shared__ float wsum[4];
  if ((t & 63) == 0) wsum[t >> 6] = s;
  __syncthreads();
  if (t == 0) {
    float mrr = (wsum[0] + wsum[1] + wsum[2] + wsum[3]) * (1.f / 1024.f);
    float loss = (spPos[0] + spNeg[0]) * (1.f / 1024.f);
    out[BATCH * 256]     = loss;
    out[BATCH * 256 + 1] = mrr;
  }
}

extern "C" void kernel_launch(void* const* d_in, const int* in_sizes, int n_in,
                              void* d_out, int out_size, void* d_ws, size_t ws_size,
                              hipStream_t stream) {
  const float* feat   = (const float*)d_in[1];
  const int* src_idx  = (const int*)d_in[2];
  const int* pos_idx  = (const int*)d_in[3];
  const int* neg_idx  = (const int*)d_in[4];
  const int* nb0      = (const int*)d_in[5];
  const int* nb1      = (const int*)d_in[6];
  const int* nb2      = (const int*)d_in[7];
  const float* ws0    = (const float*)d_in[8];
  const float* wn0    = (const float*)d_in[9];
  const float* ws1    = (const float*)d_in[10];
  const float* wn1    = (const float*)d_in[11];

  float* wsf   = (float*)d_ws;
  float* X0    = wsf;
  float* Y0    = wsf + 393216;
  float* H     = wsf + 786432;
  float* R     = wsf + 2359296;
  float* aff   = wsf + 3145728;
  float* spPos = wsf + 3146752;
  float* spNeg = wsf + 3146753;
  int*   rank  = (int*)(wsf + 3146754);
  float* out   = (float*)d_out;

  // zero the accumulators (ws is poisoned 0xAA before every timed launch)
  hipMemsetAsync(spPos, 0, (2 + BATCH) * sizeof(float), stream);

  k_transform<<<L0 / 8, 256, 0, stream>>>(feat, ws0, wn0, X0, Y0);
  k_aggregate<<<L0, 256, 0, stream>>>(X0, Y0, nb0, nb1, nb2, H);
  k_layer1<<<L0 / 16, 256, 0, stream>>>(H, ws1, wn1, R);
  k_normalize<<<L0, 256, 0, stream>>>(R);
  k_aff<<<BATCH, 256, 0, stream>>>(R, src_idx, pos_idx, out, aff, spPos);
  k_neg<<<(BATCH / 32) * (NNEG / 64), 256, 0, stream>>>(R, src_idx, neg_idx, aff, rank, spNeg);
  k_finalize<<<1, 256, 0, stream>>>(rank, spPos, spNeg, out);
}

// Round 2
// 234.328 us; speedup vs baseline: 1.3763x; 1.3763x over previous
//
#include <hip/hip_runtime.h>
#include <math.h>

// Problem constants (from reference setup_inputs)
#define L0      3072
#define DIM     128
#define BATCH   1024
#define NNEG    512

// -------- workspace layout (float offsets) --------
// X0   : 0                (3072*128)   feat @ w_self_0
// Y0   : 393216           (3072*128)   feat @ w_neigh_0
// H    : 786432           (3072*512)   [A,B | C,D] layer-1 inputs
// R    : 2359296          (3072*256)   layer-1 output, normalized in place
// aff  : 3145728          (1024)
// spPos: 3146752          (1)
// spNeg: 3146753          (1)
// rank : 3146754          (1024 ints)

// Generic half-split matmul: Out[base+r][col (+half*outHalfOff)] =
//   sum_d A[base+r][d (+half*inHalfOff)] * W_half[d][col].
// half comes from blockIdx -> A addresses are thread-uniform -> s_load.
template<int ROWS, int K>
__global__ __launch_bounds__(128) void k_mm(
    const float* __restrict__ Ain, const int lda, const int inHalfOff,
    const float* __restrict__ W0, const float* __restrict__ W1,
    float* __restrict__ Out, const int ldo, const int outHalfOff) {
  const int half = blockIdx.x & 1;
  const int base = (blockIdx.x >> 1) * ROWS;
  const int col = threadIdx.x;
  const float* __restrict__ A = Ain + base * lda + half * inHalfOff;
  const float* __restrict__ W = half ? W1 : W0;
  float acc[ROWS];
#pragma unroll
  for (int r = 0; r < ROWS; ++r) acc[r] = 0.f;
  for (int d = 0; d < K; d += 4) {
    float4 a4[ROWS];
#pragma unroll
    for (int r = 0; r < ROWS; ++r)
      a4[r] = *(const float4*)&A[r * lda + d];   // uniform address -> s_load
#pragma unroll
    for (int dd = 0; dd < 4; ++dd) {
      const float w = W[(d + dd) * 128 + col];   // coalesced 512B per block
#pragma unroll
      for (int r = 0; r < ROWS; ++r)
        acc[r] = fmaf(((const float*)&a4[r])[dd], w, acc[r]);
    }
  }
  float* __restrict__ O = Out + base * ldo + half * outHalfOff;
#pragma unroll
  for (int r = 0; r < ROWS; ++r) O[r * ldo + col] = acc[r];
}

// Fused layer-0 + layer-1 aggregation, 2 barriers total.
// H[i] = [A,B | C,D]:
//   A[c] = relu(X0[nb0[i]][c])
//   B[c] = relu(mean10_j Y0[nb1[10i+j]][c])
//   C[c] = mean10_j relu(X0[nb1[10i+j]][c])
//   D[c] = mean10_j relu(mean25_k Y0[nb2[250i+25j+k]][c])
// 128-lane group g owns j = g, g+2, ... (relu is per-j, applied locally; the
// two group partials combine after ONE barrier).
__global__ __launch_bounds__(256) void k_aggregate(
    const float* __restrict__ X0, const float* __restrict__ Y0,
    const int* __restrict__ nb0, const int* __restrict__ nb1,
    const int* __restrict__ nb2, float* __restrict__ H) {
  __shared__ int idxs[260];                 // [0..249] nb2, [250..259] nb1
  __shared__ float sA[128], sB[256], sC[256], sD[256];
  const int i = blockIdx.x;
  const int t = threadIdx.x;
  const int c = t & 127;
  const int g = t >> 7;                      // wave-uniform
  if (t < 250) idxs[t] = nb2[i * 250 + t];
  if (t < 10)  idxs[250 + t] = nb1[i * 10 + t];
  __syncthreads();

  float accD = 0.f, accB = 0.f, accC = 0.f;
  for (int j = g; j < 10; j += 2) {
    const int b2 = j * 25;
    float s = 0.f;
#pragma unroll
    for (int k = 0; k < 25; ++k) {
      const int r = __builtin_amdgcn_readfirstlane(idxs[b2 + k]);  // block-uniform
      s += Y0[r * 128 + c];                  // scalar base + lane offset
    }
    accD += fmaxf(s * 0.04f, 0.f);
    const int r1 = __builtin_amdgcn_readfirstlane(idxs[250 + j]);
    accB += Y0[r1 * 128 + c];
    accC += fmaxf(X0[r1 * 128 + c], 0.f);
  }
  if (g) sA[c] = fmaxf(X0[nb0[i] * 128 + c], 0.f);
  sB[t] = accB; sC[t] = accC; sD[t] = accD;
  __syncthreads();

  float v0, v1;
  if (t < 128) {
    v0 = sA[t];
    v1 = (sC[t] + sC[t + 128]) * 0.1f;
  } else {
    const int cc = t - 128;
    v0 = fmaxf((sB[cc] + sB[cc + 128]) * 0.1f, 0.f);
    v1 = (sD[cc] + sD[cc + 128]) * 0.1f;
  }
  H[i * 512 + t] = v0;        // t<128: A, t>=128: B
  H[i * 512 + 256 + t] = v1;  // t<128: C, t>=128: D
}

// One wave per row, float4, butterfly reduce — no LDS, no barriers.
__global__ __launch_bounds__(256) void k_normalize(float* __restrict__ R) {
  const int row = blockIdx.x * 4 + (threadIdx.x >> 6);
  const int lane = threadIdx.x & 63;
  float4 v = *(const float4*)&R[row * 256 + lane * 4];
  float s = v.x * v.x + v.y * v.y + v.z * v.z + v.w * v.w;
#pragma unroll
  for (int off = 32; off > 0; off >>= 1) s += __shfl_xor(s, off, 64);
  const float rn = rsqrtf(fmaxf(s, 1e-12f));
  v.x *= rn; v.y *= rn; v.z *= rn; v.w *= rn;
  *(float4*)&R[row * 256 + lane * 4] = v;
}

__device__ __forceinline__ float softplusf(float x) {
  return fmaxf(x, 0.f) + log1pf(expf(-fabsf(x)));
}

// K5: write src_emb to d_out; aff[b] = dot(O[src], O[pos]) with the SAME
// sequential fmaf order as k_neg (exact-tie reproduction for MRR);
// accumulate softplus(-aff).
__global__ __launch_bounds__(256) void k_aff(
    const float* __restrict__ O, const int* __restrict__ src_idx,
    const int* __restrict__ pos_idx, float* __restrict__ out_src,
    float* __restrict__ aff, float* __restrict__ spPos) {
  const int b = blockIdx.x;
  const int t = threadIdx.x;
  const int s = src_idx[b];
  out_src[b * 256 + t] = O[s * 256 + t];
  if (t == 0) {
    const int p = pos_idx[b];
    float a = 0.f;
    for (int d = 0; d < 256; ++d) a = fmaf(O[s * 256 + d], O[p * 256 + d], a);
    aff[b] = a;
    atomicAdd(spPos, softplusf(-a));
  }
}

// K6: neg_aff tile (32 src rows x 64 neg cols per block), accumulating
// softplus sum and per-row rank counts (neg_aff >= aff; ties count — the
// positive sorts last in the reference's stable double-argsort).
__global__ __launch_bounds__(256) void k_neg(
    const float* __restrict__ O, const int* __restrict__ src_idx,
    const int* __restrict__ neg_idx, const float* __restrict__ aff,
    int* __restrict__ rank, float* __restrict__ spNeg) {
  __shared__ float SL[32][129];
  __shared__ float NL[64][129];
  __shared__ float affL[32];
  __shared__ int cntL[32];
  const int t = threadIdx.x;
  const int rowBase = (blockIdx.x >> 3) * 32;
  const int colBase = (blockIdx.x & 7) * 64;
  if (t < 32) { affL[t] = aff[rowBase + t]; cntL[t] = 0; }
  const int ct = t & 31;
  const int rt = t >> 5;
  float acc[4][2];
#pragma unroll
  for (int k = 0; k < 4; ++k) { acc[k][0] = 0.f; acc[k][1] = 0.f; }
  for (int ch = 0; ch < 2; ++ch) {
    __syncthreads();
    for (int idx = t; idx < 32 * 128; idx += 256) {
      int r = idx >> 7, dd = idx & 127;
      SL[r][dd] = O[src_idx[rowBase + r] * 256 + ch * 128 + dd];
    }
    for (int idx = t; idx < 64 * 128; idx += 256) {
      int cpos = idx >> 7, dd = idx & 127;
      NL[cpos][dd] = O[neg_idx[colBase + cpos] * 256 + ch * 128 + dd];
    }
    __syncthreads();
    for (int dd = 0; dd < 128; ++dd) {
      float n0 = NL[ct][dd], n1 = NL[ct + 32][dd];
#pragma unroll
      for (int k = 0; k < 4; ++k) {
        float sv = SL[rt + 8 * k][dd];
        acc[k][0] = fmaf(sv, n0, acc[k][0]);
        acc[k][1] = fmaf(sv, n1, acc[k][1]);
      }
    }
  }
  float sp = 0.f;
#pragma unroll
  for (int k = 0; k < 4; ++k) {
    float a = affL[rt + 8 * k];
    int cnt = 0;
#pragma unroll
    for (int cc = 0; cc < 2; ++cc) {
      float v = acc[k][cc];
      sp += softplusf(v);
      cnt += (v >= a) ? 1 : 0;
    }
    if (cnt) atomicAdd(&cntL[rt + 8 * k], cnt);
  }
#pragma unroll
  for (int off = 32; off > 0; off >>= 1) sp += __shfl_down(sp, off, 64);
  if ((t & 63) == 0) atomicAdd(spNeg, sp);
  __syncthreads();
  if (t < 32) atomicAdd(&rank[rowBase + t], cntL[t]);
}

// K7: mrr + loss scalars.
__global__ __launch_bounds__(256) void k_finalize(
    const int* __restrict__ rank, const float* __restrict__ spPos,
    const float* __restrict__ spNeg, float* __restrict__ out) {
  const int t = threadIdx.x;
  float s = 0.f;
  for (int i = t; i < BATCH; i += 256) s += 1.f / (float)(rank[i] + 1);
#pragma unroll
  for (int off = 32; off > 0; off >>= 1) s += __shfl_down(s, off, 64);
  __shared__ float wsum[4];
  if ((t & 63) == 0) wsum[t >> 6] = s;
  __syncthreads();
  if (t == 0) {
    float mrr = (wsum[0] + wsum[1] + wsum[2] + wsum[3]) * (1.f / 1024.f);
    float loss = (spPos[0] + spNeg[0]) * (1.f / 1024.f);
    out[BATCH * 256]     = loss;
    out[BATCH * 256 + 1] = mrr;
  }
}

extern "C" void kernel_launch(void* const* d_in, const int* in_sizes, int n_in,
                              void* d_out, int out_size, void* d_ws, size_t ws_size,
                              hipStream_t stream) {
  const float* feat   = (const float*)d_in[1];
  const int* src_idx  = (const int*)d_in[2];
  const int* pos_idx  = (const int*)d_in[3];
  const int* neg_idx  = (const int*)d_in[4];
  const int* nb0      = (const int*)d_in[5];
  const int* nb1      = (const int*)d_in[6];
  const int* nb2      = (const int*)d_in[7];
  const float* ws0    = (const float*)d_in[8];
  const float* wn0    = (const float*)d_in[9];
  const float* ws1    = (const float*)d_in[10];
  const float* wn1    = (const float*)d_in[11];

  float* wsf   = (float*)d_ws;
  float* X0    = wsf;
  float* Y0    = wsf + 393216;
  float* H     = wsf + 786432;
  float* R     = wsf + 2359296;
  float* aff   = wsf + 3145728;
  float* spPos = wsf + 3146752;
  float* spNeg = wsf + 3146753;
  int*   rank  = (int*)(wsf + 3146754);
  float* out   = (float*)d_out;

  hipMemsetAsync(spPos, 0, (2 + BATCH) * sizeof(float), stream);

  // X0 = feat@ws0, Y0 = feat@wn0  (Y0 - X0 = 393216 floats = outHalfOff)
  k_mm<8, 128><<<(L0 / 8) * 2, 128, 0, stream>>>(feat, 128, 0, ws0, wn0,
                                                 X0, 128, 393216);
  k_aggregate<<<L0, 256, 0, stream>>>(X0, Y0, nb0, nb1, nb2, H);
  // R[:, :128] = H[:, :256]@ws1 ; R[:, 128:] = H[:, 256:]@wn1
  k_mm<8, 256><<<(L0 / 8) * 2, 128, 0, stream>>>(H, 512, 256, ws1, wn1,
                                                 R, 256, 128);
  k_normalize<<<L0 / 4, 256, 0, stream>>>(R);
  k_aff<<<BATCH, 256, 0, stream>>>(R, src_idx, pos_idx, out, aff, spPos);
  k_neg<<<(BATCH / 32) * (NNEG / 64), 256, 0, stream>>>(R, src_idx, neg_idx, aff, rank, spNeg);
  k_finalize<<<1, 256, 0, stream>>>(rank, spPos, spNeg, out);
}

// Round 3
// 216.252 us; speedup vs baseline: 1.4914x; 1.0836x over previous
//
#include <hip/hip_runtime.h>
#include <math.h>

// Problem constants (from reference setup_inputs)
#define L0      3072
#define DIM     128
#define BATCH   1024
#define NNEG    512

// -------- workspace layout (float offsets) --------
// X0   : 0         (3072*128)  feat @ w_self_0
// Y0   : 393216    (3072*128)  feat @ w_neigh_0
// H    : 786432    (3072*512)  [A,B | C,D] layer-1 inputs
// R    : 2359296   (3072*256)  layer-1 output, normalized in place
// aff  : 3145728   (1024)
// spPos: 3146752   (1)
// spNeg: 3146753   (1)
// rank : 3146754   (1024 ints)

// Half-split matmul with explicit register double-buffering.
// Out[base+r][col (+half*outHalfOff)] = sum_d A[base+r][d (+half*inHalfOff)] * W_half[d][col]
// A addresses are thread-uniform (s_load, lands in SGPRs); W loads are
// coalesced vector loads; next K-step's loads issue before current FMAs.
template<int ROWS, int K>
__global__ __launch_bounds__(128) void k_mm(
    const float* __restrict__ Ain, const int lda, const int inHalfOff,
    const float* __restrict__ W0, const float* __restrict__ W1,
    float* __restrict__ Out, const int ldo, const int outHalfOff) {
  const int half = blockIdx.x & 1;
  const int base = (blockIdx.x >> 1) * ROWS;
  const int col = threadIdx.x;
  const float* __restrict__ A = Ain + base * lda + half * inHalfOff;
  const float* __restrict__ W = (half ? W1 : W0) + col;
  float acc[ROWS];
#pragma unroll
  for (int r = 0; r < ROWS; ++r) acc[r] = 0.f;
  float4 aCur[ROWS];
  float wCur[4];
#pragma unroll
  for (int r = 0; r < ROWS; ++r) aCur[r] = *(const float4*)&A[r * lda];
#pragma unroll
  for (int dd = 0; dd < 4; ++dd) wCur[dd] = W[dd * 128];
  for (int d = 0; d < K; d += 4) {
    const int dn = (d + 4 < K) ? d + 4 : 0;   // wrap: redundant but valid
    float4 aNxt[ROWS];
    float wNxt[4];
#pragma unroll
    for (int r = 0; r < ROWS; ++r) aNxt[r] = *(const float4*)&A[r * lda + dn];
#pragma unroll
    for (int dd = 0; dd < 4; ++dd) wNxt[dd] = W[(dn + dd) * 128];
#pragma unroll
    for (int dd = 0; dd < 4; ++dd)
#pragma unroll
      for (int r = 0; r < ROWS; ++r)
        acc[r] = fmaf(((const float*)&aCur[r])[dd], wCur[dd], acc[r]);
#pragma unroll
    for (int r = 0; r < ROWS; ++r) aCur[r] = aNxt[r];
#pragma unroll
    for (int dd = 0; dd < 4; ++dd) wCur[dd] = wNxt[dd];
  }
  float* __restrict__ O = Out + base * ldo + half * outHalfOff;
#pragma unroll
  for (int r = 0; r < ROWS; ++r) O[r * ldo + col] = acc[r];
}

// Fused layer-0 + layer-1 aggregation. 640 threads = 5 groups x 128 lanes;
// group g owns j = 2g, 2g+1 (balanced). All index loads are s_load (uniform
// addresses). ONE barrier. H[i] = [A,B | C,D]:
//   A[c] = relu(X0[nb0[i]][c])
//   B[c] = relu(0.1 * sum10_j Y0[nb1[10i+j]][c])
//   C[c] = 0.1 * sum10_j relu(X0[nb1[10i+j]][c])
//   D[c] = 0.1 * sum10_j relu(0.04 * sum25_k Y0[nb2[(10i+j)*25+k]][c])
__global__ __launch_bounds__(640) void k_aggregate(
    const float* __restrict__ X0, const float* __restrict__ Y0,
    const int* __restrict__ nb0, const int* __restrict__ nb1,
    const int* __restrict__ nb2, float* __restrict__ H) {
  __shared__ float sB[5][128], sC[5][128], sD[5][128];
  const int i = blockIdx.x;
  const int t = threadIdx.x;
  const int c = t & 127;
  const int g = __builtin_amdgcn_readfirstlane(t >> 7);   // 0..4, scalar

  float accB = 0.f, accC = 0.f, accD = 0.f;
#pragma unroll
  for (int jj = 0; jj < 2; ++jj) {
    const int j = g * 2 + jj;                 // scalar
    const int r = i * 10 + j;                 // scalar
    const int* __restrict__ p = nb2 + r * 25; // uniform -> s_load
    float s = 0.f;
#pragma unroll
    for (int k = 0; k < 25; ++k) s += Y0[p[k] * 128 + c];  // saddr gathers
    accD += fmaxf(s * 0.04f, 0.f);
    const int r1 = nb1[r];                    // uniform -> s_load
    accB += Y0[r1 * 128 + c];
    accC += fmaxf(X0[r1 * 128 + c], 0.f);
  }
  sB[g][c] = accB; sC[g][c] = accC; sD[g][c] = accD;
  __syncthreads();

  if (t < 512) {
    const int q = t >> 7;                     // output quarter
    float v;
    if (q == 0) {
      v = fmaxf(X0[nb0[i] * 128 + c], 0.f);
    } else {
      const float (*S)[128] = (q == 1) ? sB : (q == 2) ? sC : sD;
      float s = S[0][c] + S[1][c] + S[2][c] + S[3][c] + S[4][c];
      v = (q == 1) ? fmaxf(s * 0.1f, 0.f) : s * 0.1f;
    }
    H[i * 512 + t] = v;
  }
}

// One wave per row, float4, butterfly reduce — no LDS, no barriers.
__global__ __launch_bounds__(256) void k_normalize(float* __restrict__ R) {
  const int row = blockIdx.x * 4 + (threadIdx.x >> 6);
  const int lane = threadIdx.x & 63;
  float4 v = *(const float4*)&R[row * 256 + lane * 4];
  float s = v.x * v.x + v.y * v.y + v.z * v.z + v.w * v.w;
#pragma unroll
  for (int off = 32; off > 0; off >>= 1) s += __shfl_xor(s, off, 64);
  const float rn = rsqrtf(fmaxf(s, 1e-12f));
  v.x *= rn; v.y *= rn; v.z *= rn; v.w *= rn;
  *(float4*)&R[row * 256 + lane * 4] = v;
}

__device__ __forceinline__ float softplusf(float x) {
  return fmaxf(x, 0.f) + log1pf(expf(-fabsf(x)));
}

// aff[b] = dot(O[src[b]], O[pos[b]]) as a single sequential fmaf chain
// d=0..255 — IDENTICAL op order to k_neg's chain (exact-tie reproduction
// for MRR). One lane per b; loads are independent of the chain.
__global__ __launch_bounds__(64) void k_aff(
    const float* __restrict__ O, const int* __restrict__ src_idx,
    const int* __restrict__ pos_idx, float* __restrict__ aff,
    float* __restrict__ spPos) {
  const int b = blockIdx.x * 64 + threadIdx.x;
  const float* __restrict__ ps = O + src_idx[b] * 256;
  const float* __restrict__ pp = O + pos_idx[b] * 256;
  float a = 0.f;
#pragma unroll 8
  for (int d = 0; d < 256; ++d) a = fmaf(ps[d], pp[d], a);
  aff[b] = a;
  float sp = softplusf(-a);
#pragma unroll
  for (int off = 32; off > 0; off >>= 1) sp += __shfl_down(sp, off, 64);
  if (threadIdx.x == 0) atomicAdd(spPos, sp);
}

// src_emb copy to d_out, float4-vectorized.
__global__ __launch_bounds__(256) void k_srccopy(
    const float* __restrict__ R, const int* __restrict__ src_idx,
    float* __restrict__ out) {
  const int idx = blockIdx.x * 256 + threadIdx.x;   // 65536 float4s
  const int b = idx >> 6, q = idx & 63;
  ((float4*)out)[b * 64 + q] = ((const float4*)R)[src_idx[b] * 64 + q];
}

// neg_aff tile (32 src rows x 64 neg cols per block): softplus sum and
// per-row rank counts (neg_aff >= aff; ties count — positive sorts last in
// the reference's stable double-argsort). Chain order per (r,c): d=0..255.
__global__ __launch_bounds__(256) void k_neg(
    const float* __restrict__ O, const int* __restrict__ src_idx,
    const int* __restrict__ neg_idx, const float* __restrict__ aff,
    int* __restrict__ rank, float* __restrict__ spNeg) {
  __shared__ float SL[32][129];
  __shared__ float NL[64][129];
  __shared__ float affL[32];
  __shared__ int cntL[32];
  const int t = threadIdx.x;
  const int rowBase = (blockIdx.x >> 3) * 32;
  const int colBase = (blockIdx.x & 7) * 64;
  if (t < 32) { affL[t] = aff[rowBase + t]; cntL[t] = 0; }
  const int ct = t & 31;
  const int rt = t >> 5;
  float acc[4][2];
#pragma unroll
  for (int k = 0; k < 4; ++k) { acc[k][0] = 0.f; acc[k][1] = 0.f; }
  for (int ch = 0; ch < 2; ++ch) {
    __syncthreads();
    for (int idx = t; idx < 32 * 128; idx += 256) {
      int r = idx >> 7, dd = idx & 127;
      SL[r][dd] = O[src_idx[rowBase + r] * 256 + ch * 128 + dd];
    }
    for (int idx = t; idx < 64 * 128; idx += 256) {
      int cpos = idx >> 7, dd = idx & 127;
      NL[cpos][dd] = O[neg_idx[colBase + cpos] * 256 + ch * 128 + dd];
    }
    __syncthreads();
    for (int dd = 0; dd < 128; ++dd) {
      float n0 = NL[ct][dd], n1 = NL[ct + 32][dd];
#pragma unroll
      for (int k = 0; k < 4; ++k) {
        float sv = SL[rt + 8 * k][dd];
        acc[k][0] = fmaf(sv, n0, acc[k][0]);
        acc[k][1] = fmaf(sv, n1, acc[k][1]);
      }
    }
  }
  float sp = 0.f;
#pragma unroll
  for (int k = 0; k < 4; ++k) {
    float a = affL[rt + 8 * k];
    int cnt = 0;
#pragma unroll
    for (int cc = 0; cc < 2; ++cc) {
      float v = acc[k][cc];
      sp += softplusf(v);
      cnt += (v >= a) ? 1 : 0;
    }
    if (cnt) atomicAdd(&cntL[rt + 8 * k], cnt);
  }
#pragma unroll
  for (int off = 32; off > 0; off >>= 1) sp += __shfl_down(sp, off, 64);
  if ((t & 63) == 0) atomicAdd(spNeg, sp);
  __syncthreads();
  if (t < 32) atomicAdd(&rank[rowBase + t], cntL[t]);
}

// mrr + loss scalars.
__global__ __launch_bounds__(256) void k_finalize(
    const int* __restrict__ rank, const float* __restrict__ spPos,
    const float* __restrict__ spNeg, float* __restrict__ out) {
  const int t = threadIdx.x;
  float s = 0.f;
  for (int i = t; i < BATCH; i += 256) s += 1.f / (float)(rank[i] + 1);
#pragma unroll
  for (int off = 32; off > 0; off >>= 1) s += __shfl_down(s, off, 64);
  __shared__ float wsum[4];
  if ((t & 63) == 0) wsum[t >> 6] = s;
  __syncthreads();
  if (t == 0) {
    float mrr = (wsum[0] + wsum[1] + wsum[2] + wsum[3]) * (1.f / 1024.f);
    float loss = (spPos[0] + spNeg[0]) * (1.f / 1024.f);
    out[BATCH * 256]     = loss;
    out[BATCH * 256 + 1] = mrr;
  }
}

extern "C" void kernel_launch(void* const* d_in, const int* in_sizes, int n_in,
                              void* d_out, int out_size, void* d_ws, size_t ws_size,
                              hipStream_t stream) {
  const float* feat   = (const float*)d_in[1];
  const int* src_idx  = (const int*)d_in[2];
  const int* pos_idx  = (const int*)d_in[3];
  const int* neg_idx  = (const int*)d_in[4];
  const int* nb0      = (const int*)d_in[5];
  const int* nb1      = (const int*)d_in[6];
  const int* nb2      = (const int*)d_in[7];
  const float* ws0    = (const float*)d_in[8];
  const float* wn0    = (const float*)d_in[9];
  const float* ws1    = (const float*)d_in[10];
  const float* wn1    = (const float*)d_in[11];

  float* wsf   = (float*)d_ws;
  float* X0    = wsf;
  float* Y0    = wsf + 393216;
  float* H     = wsf + 786432;
  float* R     = wsf + 2359296;
  float* aff   = wsf + 3145728;
  float* spPos = wsf + 3146752;
  float* spNeg = wsf + 3146753;
  int*   rank  = (int*)(wsf + 3146754);
  float* out   = (float*)d_out;

  hipMemsetAsync(spPos, 0, (2 + BATCH) * sizeof(float), stream);

  // X0 = feat@ws0, Y0 = feat@wn0  (Y0 - X0 = 393216 floats = outHalfOff)
  k_mm<4, 128><<<(L0 / 4) * 2, 128, 0, stream>>>(feat, 128, 0, ws0, wn0,
                                                 X0, 128, 393216);
  k_aggregate<<<L0, 640, 0, stream>>>(X0, Y0, nb0, nb1, nb2, H);
  // R[:, :128] = H[:, :256]@ws1 ; R[:, 128:] = H[:, 256:]@wn1
  k_mm<4, 256><<<(L0 / 4) * 2, 128, 0, stream>>>(H, 512, 256, ws1, wn1,
                                                 R, 256, 128);
  k_normalize<<<L0 / 4, 256, 0, stream>>>(R);
  k_aff<<<BATCH / 64, 64, 0, stream>>>(R, src_idx, pos_idx, aff, spPos);
  k_srccopy<<<BATCH * 64 / 256, 256, 0, stream>>>(R, src_idx, out);
  k_neg<<<(BATCH / 32) * (NNEG / 64), 256, 0, stream>>>(R, src_idx, neg_idx, aff, rank, spNeg);
  k_finalize<<<1, 256, 0, stream>>>(rank, spPos, spNeg, out);
}

// Round 4
// 177.837 us; speedup vs baseline: 1.8135x; 1.2160x over previous
//
#include <hip/hip_runtime.h>
#include <math.h>

// Problem constants (from reference setup_inputs)
#define L0      3072
#define DIM     128
#define BATCH   1024
#define NNEG    512

// -------- workspace layout (float offsets) --------
// X0   : 0         (3072*128)  feat @ w_self_0
// Y0   : 393216    (3072*128)  feat @ w_neigh_0
// H    : 786432    (3072*512)  [A,B | C,D] layer-1 inputs
// R    : 2359296   (3072*256)  layer-1 output, normalized in place
// aff  : 3145728   (1024)
// spPos: 3146752   (1)
// spNeg: 3146753   (1)
// rank : 3146754   (1024 ints)

// Half-split matmul, 6 rows x 256 cols per 256-thread block (grid 512 = 2/CU).
// A-tile staged in LDS (coalesced float4, one barrier); inner-loop A reads are
// ds_read_b128 broadcasts (in-order lgkmcnt -> fine-grained waits, unlike the
// out-of-order s_load path which forced lgkmcnt(0) drains). W double-buffered
// via global vector loads (vmcnt). Thread = 3 rows x 2 cols.
// NORM: fuse row L2-normalization into the epilogue (mm2 only).
template<int K, int AW, int HOFF, bool NORM>
__global__ __launch_bounds__(256) void k_mm(
    const float* __restrict__ Ain,
    const float* __restrict__ W0, const float* __restrict__ W1,
    float* __restrict__ Out, const int ldo, const int outHalfOff) {
  __shared__ float AT[6 * AW];
  __shared__ float rs[4][3];
  const int t = threadIdx.x;
  const int base = blockIdx.x * 6;

  {  // stage 6 rows of A (row stride == AW) as a flat float4 copy
    const float4* __restrict__ src = (const float4*)(Ain + base * AW);
    float4* __restrict__ dst = (float4*)AT;
    const int n4 = 6 * AW / 4;
#pragma unroll
    for (int i = 0; i < n4; i += 256)
      if (i + t < n4) dst[i + t] = src[i + t];
  }
  __syncthreads();

  const int half = __builtin_amdgcn_readfirstlane(t >> 7);          // 0/1
  const int rg   = __builtin_amdgcn_readfirstlane(((t & 127) >> 6) * 3); // 0/3
  const int c = t & 63;
  const float* __restrict__ W = (half ? W1 : W0) + c;
  const float* __restrict__ A0 = AT + rg * AW + half * HOFF;

  float acc[3][2];
#pragma unroll
  for (int r = 0; r < 3; ++r) { acc[r][0] = 0.f; acc[r][1] = 0.f; }

  float4 aC[3];
  float wC[8];
#pragma unroll
  for (int r = 0; r < 3; ++r) aC[r] = *(const float4*)&A0[r * AW];
#pragma unroll
  for (int i = 0; i < 4; ++i) {
    wC[i]     = W[i * 128];
    wC[4 + i] = W[i * 128 + 64];
  }
  for (int d = 0; d < K; d += 4) {
    const int dn = (d + 4 < K) ? d + 4 : 0;   // wrapped redundant prefetch
    float4 aN[3];
    float wN[8];
#pragma unroll
    for (int r = 0; r < 3; ++r) aN[r] = *(const float4*)&A0[r * AW + dn];
#pragma unroll
    for (int i = 0; i < 4; ++i) {
      wN[i]     = W[(dn + i) * 128];
      wN[4 + i] = W[(dn + i) * 128 + 64];
    }
#pragma unroll
    for (int i = 0; i < 4; ++i)
#pragma unroll
      for (int r = 0; r < 3; ++r) {
        const float av = ((const float*)&aC[r])[i];
        acc[r][0] = fmaf(av, wC[i],     acc[r][0]);
        acc[r][1] = fmaf(av, wC[4 + i], acc[r][1]);
      }
#pragma unroll
    for (int r = 0; r < 3; ++r) aC[r] = aN[r];
#pragma unroll
    for (int i = 0; i < 8; ++i) wC[i] = wN[i];
  }

  float scale[3] = {1.f, 1.f, 1.f};
  if (NORM) {
    float p[3];
#pragma unroll
    for (int r = 0; r < 3; ++r) p[r] = acc[r][0] * acc[r][0] + acc[r][1] * acc[r][1];
#pragma unroll
    for (int off = 32; off > 0; off >>= 1)
#pragma unroll
      for (int r = 0; r < 3; ++r) p[r] += __shfl_xor(p[r], off, 64);
    const int wv = t >> 6;
    if ((t & 63) == 0) { rs[wv][0] = p[0]; rs[wv][1] = p[1]; rs[wv][2] = p[2]; }
    __syncthreads();
#pragma unroll
    for (int r = 0; r < 3; ++r) {
      const float s = (rg == 0) ? (rs[0][r] + rs[2][r]) : (rs[1][r] + rs[3][r]);
      scale[r] = rsqrtf(fmaxf(s, 1e-12f));
    }
  }
  float* __restrict__ O = Out + half * outHalfOff + c;
#pragma unroll
  for (int r = 0; r < 3; ++r) {
    O[(base + rg + r) * ldo]      = acc[r][0] * scale[r];
    O[(base + rg + r) * ldo + 64] = acc[r][1] * scale[r];
  }
}

// Fused layer-0 + layer-1 aggregation. 640 threads = 5 groups x 128 lanes;
// group g owns j = 2g, 2g+1. Index loads are s_load (uniform). ONE barrier.
// H[i] = [A,B | C,D]:
//   A[c] = relu(X0[nb0[i]][c])
//   B[c] = relu(0.1 * sum10_j Y0[nb1[10i+j]][c])
//   C[c] = 0.1 * sum10_j relu(X0[nb1[10i+j]][c])
//   D[c] = 0.1 * sum10_j relu(0.04 * sum25_k Y0[nb2[(10i+j)*25+k]][c])
__global__ __launch_bounds__(640) void k_aggregate(
    const float* __restrict__ X0, const float* __restrict__ Y0,
    const int* __restrict__ nb0, const int* __restrict__ nb1,
    const int* __restrict__ nb2, float* __restrict__ H) {
  __shared__ float sB[5][128], sC[5][128], sD[5][128];
  const int i = blockIdx.x;
  const int t = threadIdx.x;
  const int c = t & 127;
  const int g = __builtin_amdgcn_readfirstlane(t >> 7);   // 0..4, scalar

  float accB = 0.f, accC = 0.f, accD = 0.f;
#pragma unroll
  for (int jj = 0; jj < 2; ++jj) {
    const int j = g * 2 + jj;                 // scalar
    const int r = i * 10 + j;                 // scalar
    const int* __restrict__ p = nb2 + r * 25; // uniform -> s_load
    float s = 0.f;
#pragma unroll
    for (int k = 0; k < 25; ++k) s += Y0[p[k] * 128 + c];  // saddr gathers
    accD += fmaxf(s * 0.04f, 0.f);
    const int r1 = nb1[r];                    // uniform -> s_load
    accB += Y0[r1 * 128 + c];
    accC += fmaxf(X0[r1 * 128 + c], 0.f);
  }
  sB[g][c] = accB; sC[g][c] = accC; sD[g][c] = accD;
  __syncthreads();

  if (t < 512) {
    const int q = t >> 7;                     // output quarter
    float v;
    if (q == 0) {
      v = fmaxf(X0[nb0[i] * 128 + c], 0.f);
    } else {
      const float (*S)[128] = (q == 1) ? sB : (q == 2) ? sC : sD;
      float s = S[0][c] + S[1][c] + S[2][c] + S[3][c] + S[4][c];
      v = (q == 1) ? fmaxf(s * 0.1f, 0.f) : s * 0.1f;
    }
    H[i * 512 + t] = v;
  }
}

__device__ __forceinline__ float softplusf(float x) {
  return fmaxf(x, 0.f) + log1pf(expf(-fabsf(x)));
}

// aff[b] = dot(O[src[b]], O[pos[b]]) as a single sequential fmaf chain
// d=0..255 — IDENTICAL op order to k_neg's chain (exact-tie reproduction
// for MRR). One lane per b.
__global__ __launch_bounds__(64) void k_aff(
    const float* __restrict__ O, const int* __restrict__ src_idx,
    const int* __restrict__ pos_idx, float* __restrict__ aff,
    float* __restrict__ spPos) {
  const int b = blockIdx.x * 64 + threadIdx.x;
  const float* __restrict__ ps = O + src_idx[b] * 256;
  const float* __restrict__ pp = O + pos_idx[b] * 256;
  float a = 0.f;
#pragma unroll 8
  for (int d = 0; d < 256; ++d) a = fmaf(ps[d], pp[d], a);
  aff[b] = a;
  float sp = softplusf(-a);
#pragma unroll
  for (int off = 32; off > 0; off >>= 1) sp += __shfl_down(sp, off, 64);
  if (threadIdx.x == 0) atomicAdd(spPos, sp);
}

// src_emb copy to d_out, float4-vectorized.
__global__ __launch_bounds__(256) void k_srccopy(
    const float* __restrict__ R, const int* __restrict__ src_idx,
    float* __restrict__ out) {
  const int idx = blockIdx.x * 256 + threadIdx.x;   // 65536 float4s
  const int b = idx >> 6, q = idx & 63;
  ((float4*)out)[b * 64 + q] = ((const float4*)R)[src_idx[b] * 64 + q];
}

// neg_aff tile (32 src rows x 64 neg cols per block): softplus sum and
// per-row rank counts (neg_aff >= aff; ties count — positive sorts last in
// the reference's stable double-argsort). Chain order per (r,c): d=0..255.
__global__ __launch_bounds__(256) void k_neg(
    const float* __restrict__ O, const int* __restrict__ src_idx,
    const int* __restrict__ neg_idx, const float* __restrict__ aff,
    int* __restrict__ rank, float* __restrict__ spNeg) {
  __shared__ float SL[32][129];
  __shared__ float NL[64][129];
  __shared__ float affL[32];
  __shared__ int cntL[32];
  const int t = threadIdx.x;
  const int rowBase = (blockIdx.x >> 3) * 32;
  const int colBase = (blockIdx.x & 7) * 64;
  if (t < 32) { affL[t] = aff[rowBase + t]; cntL[t] = 0; }
  const int ct = t & 31;
  const int rt = t >> 5;
  float acc[4][2];
#pragma unroll
  for (int k = 0; k < 4; ++k) { acc[k][0] = 0.f; acc[k][1] = 0.f; }
  for (int ch = 0; ch < 2; ++ch) {
    __syncthreads();
    for (int idx = t; idx < 32 * 128; idx += 256) {
      int r = idx >> 7, dd = idx & 127;
      SL[r][dd] = O[src_idx[rowBase + r] * 256 + ch * 128 + dd];
    }
    for (int idx = t; idx < 64 * 128; idx += 256) {
      int cpos = idx >> 7, dd = idx & 127;
      NL[cpos][dd] = O[neg_idx[colBase + cpos] * 256 + ch * 128 + dd];
    }
    __syncthreads();
    for (int dd = 0; dd < 128; ++dd) {
      float n0 = NL[ct][dd], n1 = NL[ct + 32][dd];
#pragma unroll
      for (int k = 0; k < 4; ++k) {
        float sv = SL[rt + 8 * k][dd];
        acc[k][0] = fmaf(sv, n0, acc[k][0]);
        acc[k][1] = fmaf(sv, n1, acc[k][1]);
      }
    }
  }
  float sp = 0.f;
#pragma unroll
  for (int k = 0; k < 4; ++k) {
    float a = affL[rt + 8 * k];
    int cnt = 0;
#pragma unroll
    for (int cc = 0; cc < 2; ++cc) {
      float v = acc[k][cc];
      sp += softplusf(v);
      cnt += (v >= a) ? 1 : 0;
    }
    if (cnt) atomicAdd(&cntL[rt + 8 * k], cnt);
  }
#pragma unroll
  for (int off = 32; off > 0; off >>= 1) sp += __shfl_down(sp, off, 64);
  if ((t & 63) == 0) atomicAdd(spNeg, sp);
  __syncthreads();
  if (t < 32) atomicAdd(&rank[rowBase + t], cntL[t]);
}

// mrr + loss scalars.
__global__ __launch_bounds__(256) void k_finalize(
    const int* __restrict__ rank, const float* __restrict__ spPos,
    const float* __restrict__ spNeg, float* __restrict__ out) {
  const int t = threadIdx.x;
  float s = 0.f;
  for (int i = t; i < BATCH; i += 256) s += 1.f / (float)(rank[i] + 1);
#pragma unroll
  for (int off = 32; off > 0; off >>= 1) s += __shfl_down(s, off, 64);
  __shared__ float wsum[4];
  if ((t & 63) == 0) wsum[t >> 6] = s;
  __syncthreads();
  if (t == 0) {
    float mrr = (wsum[0] + wsum[1] + wsum[2] + wsum[3]) * (1.f / 1024.f);
    float loss = (spPos[0] + spNeg[0]) * (1.f / 1024.f);
    out[BATCH * 256]     = loss;
    out[BATCH * 256 + 1] = mrr;
  }
}

extern "C" void kernel_launch(void* const* d_in, const int* in_sizes, int n_in,
                              void* d_out, int out_size, void* d_ws, size_t ws_size,
                              hipStream_t stream) {
  const float* feat   = (const float*)d_in[1];
  const int* src_idx  = (const int*)d_in[2];
  const int* pos_idx  = (const int*)d_in[3];
  const int* neg_idx  = (const int*)d_in[4];
  const int* nb0      = (const int*)d_in[5];
  const int* nb1      = (const int*)d_in[6];
  const int* nb2      = (const int*)d_in[7];
  const float* ws0    = (const float*)d_in[8];
  const float* wn0    = (const float*)d_in[9];
  const float* ws1    = (const float*)d_in[10];
  const float* wn1    = (const float*)d_in[11];

  float* wsf   = (float*)d_ws;
  float* X0    = wsf;
  float* Y0    = wsf + 393216;
  float* H     = wsf + 786432;
  float* R     = wsf + 2359296;
  float* aff   = wsf + 3145728;
  float* spPos = wsf + 3146752;
  float* spNeg = wsf + 3146753;
  int*   rank  = (int*)(wsf + 3146754);
  float* out   = (float*)d_out;

  hipMemsetAsync(spPos, 0, (2 + BATCH) * sizeof(float), stream);

  // X0 = feat@ws0, Y0 = feat@wn0 (same A for both halves; Y0-X0 = 393216)
  k_mm<128, 128, 0, false><<<L0 / 6, 256, 0, stream>>>(feat, ws0, wn0,
                                                       X0, 128, 393216);
  k_aggregate<<<L0, 640, 0, stream>>>(X0, Y0, nb0, nb1, nb2, H);
  // R[:, :128] = H[:, :256]@ws1 ; R[:, 128:] = H[:, 256:]@wn1 ; + L2-norm
  k_mm<256, 512, 256, true><<<L0 / 6, 256, 0, stream>>>(H, ws1, wn1,
                                                        R, 256, 128);
  k_aff<<<BATCH / 64, 64, 0, stream>>>(R, src_idx, pos_idx, aff, spPos);
  k_srccopy<<<BATCH * 64 / 256, 256, 0, stream>>>(R, src_idx, out);
  k_neg<<<(BATCH / 32) * (NNEG / 64), 256, 0, stream>>>(R, src_idx, neg_idx, aff, rank, spNeg);
  k_finalize<<<1, 256, 0, stream>>>(rank, spPos, spNeg, out);
}